// Round 10
// baseline (214.882 us; speedup 1.0000x reference)
//
#include <hip/hip_runtime.h>
#include <hip/hip_bf16.h>
#include <math.h>

typedef short bf16x8 __attribute__((ext_vector_type(8)));
typedef float f32x4 __attribute__((ext_vector_type(4)));
typedef unsigned short u16;

__device__ inline float b2f(u16 h) {
    unsigned int u = ((unsigned int)h) << 16;
    float f;
    __builtin_memcpy(&f, &u, 4);
    return f;
}

__device__ inline u16 f2b(float f) {
    unsigned int u;
    __builtin_memcpy(&u, &f, 4);
    unsigned int lsb = (u >> 16) & 1u;
    u += 0x7fffu + lsb;
    return (u16)(u >> 16);
}

// async 16B global -> LDS (wave-uniform base + lane*16 at all call sites)
__device__ __forceinline__ void gl2lds16(const u16* g, u16* l) {
    __builtin_amdgcn_global_load_lds(
        (const __attribute__((address_space(1))) unsigned int*)g,
        (__attribute__((address_space(3))) unsigned int*)l,
        16, 0, 0);
}

#define PITCH 72   // wtrans scratch pitch

// log2(e) / 8  (softmax temperature sqrt(64)=8 folded into Q projection)
#define QSCALE 0.18033688011112042f

// ---------------------------------------------------------------------------
// Launch 1: prep = cvt (blocks 0..8191) U wtrans (8192..8447) U pool
// (8448..9471, reading x f32 DIRECTLY -- no xb dependency, and numerically
// closer to the f32 reference). All three are input-independent.
// ---------------------------------------------------------------------------
__global__ __launch_bounds__(256) void prep_kernel(const float* __restrict__ x,
                                                   u16* __restrict__ xb,
                                                   const float* __restrict__ w0,
                                                   const float* __restrict__ w1,
                                                   const float* __restrict__ w2,
                                                   const float* __restrict__ w3,
                                                   u16* __restrict__ wt,
                                                   u16* __restrict__ xp) {
    __shared__ u16 T[64 * PITCH];
    int tid = threadIdx.x;
    if (blockIdx.x < 8192) {            // ---- cvt: x f32 -> bf16
        int idx = blockIdx.x * 256 + tid;   // 2,097,152 float4s
        float4 v = ((const float4*)x)[idx];
        ushort4 o;
        o.x = f2b(v.x); o.y = f2b(v.y); o.z = f2b(v.z); o.w = f2b(v.w);
        ((ushort4*)xb)[idx] = o;
        return;
    }
    if (blockIdx.x >= 8448) {           // ---- pool: TF avg 3x3/s2 SAME, f32 in
        int idx = (blockIdx.x - 8448) * 256 + tid;  // 262,144 = (4,32,32,64)
        int c8 = idx & 63;
        int j = (idx >> 6) & 31;
        int i = (idx >> 11) & 31;
        int b = idx >> 16;
        int r0 = 2 * i, c0 = 2 * j;
        int rmax = min(r0 + 3, 64), cmax = min(c0 + 3, 64);
        float acc[8] = {};
        for (int r = r0; r < rmax; ++r)
            for (int cc = c0; cc < cmax; ++cc) {
                const float* p = &x[(size_t)((((b << 6) + r) << 6) + cc) * 512 + c8 * 8];
                float4 v0 = *(const float4*)p;
                float4 v1 = *(const float4*)(p + 4);
                acc[0] += v0.x; acc[1] += v0.y; acc[2] += v0.z; acc[3] += v0.w;
                acc[4] += v1.x; acc[5] += v1.y; acc[6] += v1.z; acc[7] += v1.w;
            }
        float inv = 1.f / (float)((rmax - r0) * (cmax - c0));
        u16 o[8];
#pragma unroll
        for (int t = 0; t < 8; ++t) o[t] = f2b(acc[t] * inv);
        *(int4*)(&xp[(size_t)idx * 8]) = *(int4*)o;
        return;
    }
    // ---- wtrans: transpose+convert four 512x512 f32 weights to WT[n][k]
    int t5 = blockIdx.x - 8192;         // 0..255
    int bx = t5 & 7, by = (t5 >> 3) & 7, bz = t5 >> 6;
    const float* W = bz == 0 ? w0 : bz == 1 ? w1 : bz == 2 ? w2 : w3;
    u16* WT = wt + (size_t)bz * 262144;
    int nB = bx * 64, kB = by * 64;
#pragma unroll
    for (int t = 0; t < 4; ++t) {
        int e = tid + t * 256;
        int r = e >> 4, c4 = (e & 15) * 4;
        float4 v = *(const float4*)(&W[(size_t)(kB + r) * 512 + nB + c4]);
        u16* dst = &T[r * PITCH + c4];
        dst[0] = f2b(v.x); dst[1] = f2b(v.y); dst[2] = f2b(v.z); dst[3] = f2b(v.w);
    }
    __syncthreads();
    int n = tid & 63, kg = tid >> 6;
#pragma unroll
    for (int p = 0; p < 2; ++p) {
        int k0 = (kg + p * 4) * 8;
        u16 tmp[8];
#pragma unroll
        for (int i = 0; i < 8; ++i) tmp[i] = T[(k0 + i) * PITCH + n];
        *(int4*)(&WT[(size_t)(nB + n) * 512 + kB + k0]) = *(int4*)tmp;
    }
}

// ---------------------------------------------------------------------------
// GEMM body (round-6 verified): tile 64xBN, BK=64, 4 waves, SINGLE-buffer
// LDS (round-7 A/B: explicit dbuf cost occupancy 4->3 and REGRESSED +5.5us).
// XCD remap: bid = nBlk*GY + mBlk, GY % 8 == 0 -> A-panel sharers on one XCD.
// OM=0: bf16*oscale. OM=1: f32+residual. OM=3: fused K|V split at col 512.
// ---------------------------------------------------------------------------
template <int OM, int BN, int GY>
__device__ __forceinline__ void gemm_body(int bid,
                                          const u16* __restrict__ A,
                                          const u16* __restrict__ WT,
                                          const float* __restrict__ bias,
                                          const float* __restrict__ bias2res,
                                          void* __restrict__ Cv,
                                          void* __restrict__ Cv2,
                                          float oscale,
                                          u16* At, u16* Bt) {
    int tid = threadIdx.x, lane = tid & 63, wave = tid >> 6;
    int q = lane >> 4, l16 = lane & 15;
    constexpr int MI = (BN == 128) ? 2 : 1;
    int wm, wn;
    if constexpr (BN == 128) { wm = wave & 1; wn = wave >> 1; }
    else                     { wm = wave;     wn = 0; }
    int nBlk = bid / GY;
    int mBlk = bid - nBlk * GY;
    int nBase = nBlk * BN, mBase = mBlk * 64;
    f32x4 acc[MI][4] = {};

    for (int kk = 0; kk < 512; kk += 64) {
        __syncthreads();
#pragma unroll
        for (int t = 0; t < 2; ++t) {             // At: 512 chunk slots
            int c = tid + t * 256;
            int m = c >> 3, kc = (c & 7) ^ (m & 7);
            gl2lds16(&A[(size_t)(mBase + m) * 512 + kk + kc * 8], &At[c * 8]);
        }
#pragma unroll
        for (int t = 0; t < BN / 32; ++t) {       // Bt: BN*8 chunk slots
            int c = tid + t * 256;
            int m = c >> 3, kc = (c & 7) ^ (m & 7);
            gl2lds16(&WT[(size_t)(nBase + m) * 512 + kk + kc * 8], &Bt[c * 8]);
        }
        __syncthreads();
#pragma unroll
        for (int ds = 0; ds < 2; ++ds) {
            bf16x8 a[MI], b[4];
#pragma unroll
            for (int i = 0; i < MI; ++i) {
                int ma = (BN == 128 ? wm * 32 : wm * 16) + i * 16 + l16;
                a[i] = *(bf16x8*)(&At[ma * 64 + ((((ds << 2) + q) ^ (ma & 7)) << 3)]);
            }
#pragma unroll
            for (int j = 0; j < 4; ++j) {
                int nb = wn * 64 + j * 16 + l16;
                b[j] = *(bf16x8*)(&Bt[nb * 64 + ((((ds << 2) + q) ^ (nb & 7)) << 3)]);
            }
#pragma unroll
            for (int i = 0; i < MI; ++i)
#pragma unroll
                for (int j = 0; j < 4; ++j)
                    acc[i][j] = __builtin_amdgcn_mfma_f32_16x16x32_bf16(a[i], b[j], acc[i][j], 0, 0, 0);
        }
    }

    bool isK = (OM != 3) || (nBase < 512);
#pragma unroll
    for (int j = 0; j < 4; ++j) {
        int col = nBase + wn * 64 + j * 16 + l16;
        float bv;
        if constexpr (OM == 3) bv = isK ? bias[col] : bias2res[col - 512];
        else bv = bias[col];
#pragma unroll
        for (int i = 0; i < MI; ++i) {
#pragma unroll
            for (int r = 0; r < 4; ++r) {
                int row = mBase + (BN == 128 ? wm * 32 : wm * 16) + i * 16 + q * 4 + r;
                float v = acc[i][j][r] + bv;
                if constexpr (OM == 1) {
                    v += bias2res[(size_t)row * 512 + col];
                    ((float*)Cv)[(size_t)row * 512 + col] = v;
                } else if constexpr (OM == 0) {
                    ((u16*)Cv)[(size_t)row * 512 + col] = f2b(v * oscale);
                } else {
                    if (isK) {
                        ((u16*)Cv)[(size_t)row * 512 + col] = f2b(v);
                    } else {
                        int colv = col - 512;
                        int g = row >> 7, m2 = ((row & 127) << 3) + (colv >> 6), d = colv & 63;
                        ((u16*)Cv2)[(size_t)((g << 6) + d) * 1024 + m2] = f2b(v);
                    }
                }
            }
        }
    }
}

// ---------------------------------------------------------------------------
// Launch 2: Q-GEMM (blocks 0..1023) U KV-GEMM (1024..2047). Both depend only
// on L1's outputs -> co-run; overlapping ramp/drain replaces the former
// serial L2->L3 boundary. LDS = max(24, 16) KB -> 4 blocks/CU.
// ---------------------------------------------------------------------------
__global__ __launch_bounds__(256, 4) void qkv_kernel(const u16* __restrict__ xb,
                                                     const u16* __restrict__ xp,
                                                     const u16* __restrict__ wT,
                                                     const float* __restrict__ b_q,
                                                     const float* __restrict__ b_k,
                                                     const float* __restrict__ b_v,
                                                     u16* __restrict__ Qw,
                                                     u16* __restrict__ Kw,
                                                     u16* __restrict__ VwT) {
    __shared__ __align__(16) u16 At[64 * 64];
    __shared__ __align__(16) u16 Bt[128 * 64];
    int gid = blockIdx.x;
    if (gid < 1024) {
        gemm_body<0, 128, 256>(gid, xb, wT, b_q, nullptr, Qw, nullptr, QSCALE, At, Bt);
    } else {
        gemm_body<3, 64, 64>(gid - 1024, xp, wT + 262144, b_k, b_v, Kw, VwT, 1.0f, At, Bt);
    }
}

// Launch 5: output projection + f32 residual.
__global__ __launch_bounds__(256, 4) void gemm_o_kernel(const u16* __restrict__ Ow,
                                                        const u16* __restrict__ wTo,
                                                        const float* __restrict__ b_o,
                                                        const float* __restrict__ xres,
                                                        float* __restrict__ out) {
    __shared__ __align__(16) u16 At[64 * 64];
    __shared__ __align__(16) u16 Bt[128 * 64];
    gemm_body<1, 128, 256>(blockIdx.x, Ow, wTo, b_o, xres, out, nullptr, 1.0f, At, Bt);
}

// ---------------------------------------------------------------------------
// Launches 3a/3b: flash attention (round-9 verified dbuf body; VGPR 52, no
// spill). QBLK=128, KVBLK=64 double-buffered. Split into 2 dispatches of 16
// q-tiles each (DIAGNOSTIC: halves attn dur to ~26 us so all five pipeline
// stages surface in rocprof top-5 with full counters). XCD pinning kept
// (g = blockIdx.x -> XCD = g&7, identical in both halves).
// ---------------------------------------------------------------------------
__global__ __launch_bounds__(256, 4) void attn_kernel(const u16* __restrict__ Q,
                                                      const u16* __restrict__ K,
                                                      const u16* __restrict__ VT_g,
                                                      u16* __restrict__ O,
                                                      int qt0) {
    int g = blockIdx.x;       // XCD = g & 7 (round-robin by linear id)
    int qtile = qt0 + blockIdx.y;
    const u16* Qg = Q + (size_t)g * 262144;
    const u16* Kg = K + (size_t)g * 65536;
    const u16* Vt = VT_g + (size_t)g * 65536;   // [d][m], pitch 1024
    u16* Og = O + (size_t)g * 262144;

    __shared__ __align__(16) u16 Kt[2][64 * 64];   // XOR-8 swizzled [m][d]
    __shared__ __align__(16) u16 VTs[2][64 * 64];  // XOR-8 swizzled [d][m]
    __shared__ __align__(16) u16 Pt[64 * 64];      // XOR-4dw swizzled [n][m]

    int tid = threadIdx.x, lane = tid & 63, wave = tid >> 6;
    int q = lane >> 4, l16 = lane & 15;
    int n0 = qtile * 128;
    int pkey = (l16 & 7) << 2;            // dword-XOR key for Pt
    int prow = (wave * 16 + l16) * 32;    // Pt row base (dwords)
    int* Pt32 = (int*)Pt;

    bf16x8 qf[2][2];
#pragma unroll
    for (int s = 0; s < 2; ++s)
#pragma unroll
        for (int ds = 0; ds < 2; ++ds)
            qf[s][ds] = *(const bf16x8*)(
                &Qg[(size_t)(n0 + s * 64 + wave * 16 + l16) * 64 + ds * 32 + q * 8]);

    f32x4 oacc[2][4] = {};
    float rsum[2] = {0.f, 0.f};

    auto stage = [&](int buf, int kb) {
#pragma unroll
        for (int t = 0; t < 2; ++t) {
            int c = tid + t * 256;                // slot 0..511
            int m = c >> 3, kc = (c & 7) ^ (m & 7);
            gl2lds16(&Kg[(size_t)(kb * 64 + m) * 64 + kc * 8], &Kt[buf][c * 8]);
            gl2lds16(&Vt[(size_t)m * 1024 + kb * 64 + kc * 8], &VTs[buf][c * 8]);
        }
    };

    stage(0, 0);
    asm volatile("s_waitcnt vmcnt(0)" ::: "memory");
    __syncthreads();

    int cur = 0;
#pragma unroll 1
    for (int kb = 0; kb < 16; ++kb) {
        if (kb < 15) stage(cur ^ 1, kb + 1);      // next tile's loads in flight
        const u16* KtB = Kt[cur];
        const u16* VTsB = VTs[cur];
#pragma unroll
        for (int s = 0; s < 2; ++s) {
            // S^T block; p = exp2(z); packed b64 write to Pt[n][m]
#pragma unroll
            for (int cb = 0; cb < 4; ++cb) {
                int m = cb * 16 + l16;
                bf16x8 kf0 = *(const bf16x8*)(&KtB[m * 64 + ((q ^ (m & 7)) << 3)]);
                bf16x8 kf1 = *(const bf16x8*)(&KtB[m * 64 + (((4 + q) ^ (m & 7)) << 3)]);
                f32x4 z = {};
                __builtin_amdgcn_s_setprio(1);
                z = __builtin_amdgcn_mfma_f32_16x16x32_bf16(kf0, qf[s][0], z, 0, 0, 0);
                z = __builtin_amdgcn_mfma_f32_16x16x32_bf16(kf1, qf[s][1], z, 0, 0, 0);
                __builtin_amdgcn_s_setprio(0);
                float p0 = __builtin_amdgcn_exp2f(z[0]);
                float p1 = __builtin_amdgcn_exp2f(z[1]);
                float p2 = __builtin_amdgcn_exp2f(z[2]);
                float p3 = __builtin_amdgcn_exp2f(z[3]);
                rsum[s] += (p0 + p1) + (p2 + p3);
                unsigned w0, w1;
                asm("v_cvt_pk_bf16_f32 %0, %1, %2" : "=v"(w0) : "v"(p0), "v"(p1));
                asm("v_cvt_pk_bf16_f32 %0, %1, %2" : "=v"(w1) : "v"(p2), "v"(p3));
                int2 w;
                w.x = (int)w0;
                w.y = (int)w1;
                int pd = (cb * 8 + q * 2) ^ pkey;
                *(int2*)(&Pt32[prow + pd]) = w;
            }
            // O += P V (same wave wrote Pt rows; DS in-order, no barrier)
#pragma unroll
            for (int ds = 0; ds < 2; ++ds) {
                int pd = (ds * 16 + q * 4) ^ pkey;
                bf16x8 ap = *(bf16x8*)(&Pt32[prow + pd]);
                __builtin_amdgcn_s_setprio(1);
#pragma unroll
                for (int db = 0; db < 4; ++db) {
                    int dd = db * 16 + l16;
                    int jj = ds * 4 + q;
                    bf16x8 vb = *(const bf16x8*)(&VTsB[dd * 64 + ((jj ^ (dd & 7)) << 3)]);
                    oacc[s][db] = __builtin_amdgcn_mfma_f32_16x16x32_bf16(ap, vb, oacc[s][db], 0, 0, 0);
                }
                __builtin_amdgcn_s_setprio(0);
            }
        }
        asm volatile("s_waitcnt vmcnt(0)" ::: "memory");
        __syncthreads();
        cur ^= 1;
    }

    // epilogue: rsum at row n=l16 (partial over quads) -> reduce over quads,
    // then fetch row (q*4+r)'s total via shfl, normalize, store.
#pragma unroll
    for (int s = 0; s < 2; ++s) {
        float v = rsum[s];
        v += __shfl_xor(v, 16, 64);
        v += __shfl_xor(v, 32, 64);
        rsum[s] = v;
    }
    float inv[2][4];
#pragma unroll
    for (int s = 0; s < 2; ++s)
#pragma unroll
        for (int r = 0; r < 4; ++r)
            inv[s][r] = 1.f / __shfl(rsum[s], q * 4 + r, 64);
#pragma unroll
    for (int s = 0; s < 2; ++s)
#pragma unroll
        for (int db = 0; db < 4; ++db)
#pragma unroll
            for (int r = 0; r < 4; ++r) {
                int row = n0 + s * 64 + wave * 16 + q * 4 + r;
                Og[(size_t)row * 64 + db * 16 + l16] = f2b(oacc[s][db][r] * inv[s][r]);
            }
}

// ---------------------------------------------------------------------------
extern "C" void kernel_launch(void* const* d_in, const int* in_sizes, int n_in,
                              void* d_out, int out_size, void* d_ws, size_t ws_size,
                              hipStream_t stream) {
    const float* x   = (const float*)d_in[0];
    const float* w_q = (const float*)d_in[1];
    const float* b_q = (const float*)d_in[2];
    const float* w_k = (const float*)d_in[3];
    const float* b_k = (const float*)d_in[4];
    const float* w_v = (const float*)d_in[5];
    const float* b_v = (const float*)d_in[6];
    const float* w_o = (const float*)d_in[7];
    const float* b_o = (const float*)d_in[8];
    float* out = (float*)d_out;

    char* ws = (char*)d_ws;
    u16* xb  = (u16*)(ws);                        // 16 MB (16384,512) bf16
    u16* xp  = (u16*)(ws + (16ull << 20));        //  4 MB (4096,512)
    u16* Qw  = (u16*)(ws + (20ull << 20));        // 16 MB (16384,512)
    u16* Kw  = (u16*)(ws + (36ull << 20));        //  4 MB (4096,512)
    u16* VwT = (u16*)(ws + (40ull << 20));        //  4 MB 32x(64,1024)
    u16* wT  = (u16*)(ws + (44ull << 20));        //  2 MB: 4 x 512x512 bf16
    u16* Ow  = xb;  // alias: xb's last reader (Q-GEMM, L2) precedes attn's write

    // L1: cvt U wtrans U pool (pool reads x f32 directly)
    prep_kernel<<<9472, 256, 0, stream>>>(x, xb, w_q, w_k, w_v, w_o, wT, xp);
    // L2: Q projection U fused K|V projection (co-resident)
    qkv_kernel<<<2048, 256, 0, stream>>>(xb, xp, wT, b_q, b_k, b_v, Qw, Kw, VwT);
    // L3a/L3b: attention, 2 halves (diagnostic split -> all stages in top-5)
    attn_kernel<<<dim3(32, 16), 256, 0, stream>>>(Qw, Kw, VwT, Ow, 0);
    attn_kernel<<<dim3(32, 16), 256, 0, stream>>>(Qw, Kw, VwT, Ow, 16);
    // L5: output projection + f32 residual
    gemm_o_kernel<<<1024, 256, 0, stream>>>(Ow, wT + 786432, b_o, x, out);
}

// Round 11
// 194.484 us; speedup vs baseline: 1.1049x; 1.1049x over previous
//
#include <hip/hip_runtime.h>
#include <hip/hip_bf16.h>
#include <math.h>

typedef short bf16x8 __attribute__((ext_vector_type(8)));
typedef float f32x4 __attribute__((ext_vector_type(4)));
typedef unsigned short u16;

__device__ inline float b2f(u16 h) {
    unsigned int u = ((unsigned int)h) << 16;
    float f;
    __builtin_memcpy(&f, &u, 4);
    return f;
}

__device__ inline u16 f2b(float f) {
    unsigned int u;
    __builtin_memcpy(&u, &f, 4);
    unsigned int lsb = (u >> 16) & 1u;
    u += 0x7fffu + lsb;
    return (u16)(u >> 16);
}

// async 16B global -> LDS (wave-uniform base + lane*16 at all call sites)
__device__ __forceinline__ void gl2lds16(const u16* g, u16* l) {
    __builtin_amdgcn_global_load_lds(
        (const __attribute__((address_space(1))) unsigned int*)g,
        (__attribute__((address_space(3))) unsigned int*)l,
        16, 0, 0);
}

#define PITCH 72   // wtrans scratch pitch

// log2(e) / 8  (softmax temperature sqrt(64)=8 folded into Q projection)
#define QSCALE 0.18033688011112042f

// ---------------------------------------------------------------------------
// Launch 1: prep = wtrans (blocks 0..255) U pool (256..1279). cvt stage is
// ELIMINATED (round 11): Q-GEMM stages f32 x directly and converts in-reg;
// pool reads f32 x (round-10 verified, absmax improved). Saves cvt's 50 MB
// of stage traffic and one serial launch boundary.
// ---------------------------------------------------------------------------
__global__ __launch_bounds__(256) void prep_kernel(const float* __restrict__ x,
                                                   const float* __restrict__ w0,
                                                   const float* __restrict__ w1,
                                                   const float* __restrict__ w2,
                                                   const float* __restrict__ w3,
                                                   u16* __restrict__ wt,
                                                   u16* __restrict__ xp) {
    __shared__ u16 T[64 * PITCH];
    int tid = threadIdx.x;
    if (blockIdx.x >= 256) {            // ---- pool: TF avg 3x3/s2 SAME, f32 in
        int idx = (blockIdx.x - 256) * 256 + tid;   // 262,144 = (4,32,32,64)
        int c8 = idx & 63;
        int j = (idx >> 6) & 31;
        int i = (idx >> 11) & 31;
        int b = idx >> 16;
        int r0 = 2 * i, c0 = 2 * j;
        int rmax = min(r0 + 3, 64), cmax = min(c0 + 3, 64);
        float acc[8] = {};
        for (int r = r0; r < rmax; ++r)
            for (int cc = c0; cc < cmax; ++cc) {
                const float* p = &x[(size_t)((((b << 6) + r) << 6) + cc) * 512 + c8 * 8];
                float4 v0 = *(const float4*)p;
                float4 v1 = *(const float4*)(p + 4);
                acc[0] += v0.x; acc[1] += v0.y; acc[2] += v0.z; acc[3] += v0.w;
                acc[4] += v1.x; acc[5] += v1.y; acc[6] += v1.z; acc[7] += v1.w;
            }
        float inv = 1.f / (float)((rmax - r0) * (cmax - c0));
        u16 o[8];
#pragma unroll
        for (int t = 0; t < 8; ++t) o[t] = f2b(acc[t] * inv);
        *(int4*)(&xp[(size_t)idx * 8]) = *(int4*)o;
        return;
    }
    // ---- wtrans: transpose+convert four 512x512 f32 weights to WT[n][k]
    int t5 = blockIdx.x;                // 0..255
    int bx = t5 & 7, by = (t5 >> 3) & 7, bz = t5 >> 6;
    const float* W = bz == 0 ? w0 : bz == 1 ? w1 : bz == 2 ? w2 : w3;
    u16* WT = wt + (size_t)bz * 262144;
    int nB = bx * 64, kB = by * 64;
#pragma unroll
    for (int t = 0; t < 4; ++t) {
        int e = tid + t * 256;
        int r = e >> 4, c4 = (e & 15) * 4;
        float4 v = *(const float4*)(&W[(size_t)(kB + r) * 512 + nB + c4]);
        u16* dst = &T[r * PITCH + c4];
        dst[0] = f2b(v.x); dst[1] = f2b(v.y); dst[2] = f2b(v.z); dst[3] = f2b(v.w);
    }
    __syncthreads();
    int n = tid & 63, kg = tid >> 6;
#pragma unroll
    for (int p = 0; p < 2; ++p) {
        int k0 = (kg + p * 4) * 8;
        u16 tmp[8];
#pragma unroll
        for (int i = 0; i < 8; ++i) tmp[i] = T[(k0 + i) * PITCH + n];
        *(int4*)(&WT[(size_t)(nB + n) * 512 + kB + k0]) = *(int4*)tmp;
    }
}

// ---------------------------------------------------------------------------
// GEMM body (round-6 verified structure): tile 64xBN, BK=64, 4 waves,
// SINGLE-buffer LDS (round-7: dbuf regressed). AF32: A is f32 in global
// (x itself); staged as f32 tiles (16 KB, XOR-16 chunk swizzle), fragments
// converted f32->bf16 in-register via v_cvt_pk_bf16_f32 (RNE -- bit-identical
// to the old cvt_kernel's f2b). XCD remap: bid = nBlk*GY + mBlk, GY%8==0.
// OM=0: bf16*oscale. OM=1: f32+residual. OM=3: fused K|V split at col 512.
// ---------------------------------------------------------------------------
template <int OM, int BN, int GY, bool AF32>
__device__ __forceinline__ void gemm_body(int bid,
                                          const void* __restrict__ Av,
                                          const u16* __restrict__ WT,
                                          const float* __restrict__ bias,
                                          const float* __restrict__ bias2res,
                                          void* __restrict__ Cv,
                                          void* __restrict__ Cv2,
                                          float oscale,
                                          u16* At, u16* Bt) {
    int tid = threadIdx.x, lane = tid & 63, wave = tid >> 6;
    int q = lane >> 4, l16 = lane & 15;
    constexpr int MI = (BN == 128) ? 2 : 1;
    int wm, wn;
    if constexpr (BN == 128) { wm = wave & 1; wn = wave >> 1; }
    else                     { wm = wave;     wn = 0; }
    int nBlk = bid / GY;
    int mBlk = bid - nBlk * GY;
    int nBase = nBlk * BN, mBase = mBlk * 64;
    f32x4 acc[MI][4] = {};

    for (int kk = 0; kk < 512; kk += 64) {
        __syncthreads();
        if constexpr (AF32) {
            const float* Af = (const float*)Av;
#pragma unroll
            for (int t = 0; t < 4; ++t) {         // At f32: 1024 16B slots
                int c = tid + t * 256;
                int m = c >> 4, kc = (c & 15) ^ (m & 15);
                gl2lds16((const u16*)&Af[(size_t)(mBase + m) * 512 + kk + kc * 4],
                         &At[c * 8]);
            }
        } else {
            const u16* Ab = (const u16*)Av;
#pragma unroll
            for (int t = 0; t < 2; ++t) {         // At bf16: 512 slots
                int c = tid + t * 256;
                int m = c >> 3, kc = (c & 7) ^ (m & 7);
                gl2lds16(&Ab[(size_t)(mBase + m) * 512 + kk + kc * 8], &At[c * 8]);
            }
        }
#pragma unroll
        for (int t = 0; t < BN / 32; ++t) {       // Bt: BN*8 chunk slots
            int c = tid + t * 256;
            int m = c >> 3, kc = (c & 7) ^ (m & 7);
            gl2lds16(&WT[(size_t)(nBase + m) * 512 + kk + kc * 8], &Bt[c * 8]);
        }
        __syncthreads();
#pragma unroll
        for (int ds = 0; ds < 2; ++ds) {
            bf16x8 a[MI], b[4];
#pragma unroll
            for (int i = 0; i < MI; ++i) {
                int ma = (BN == 128 ? wm * 32 : wm * 16) + i * 16 + l16;
                if constexpr (AF32) {
                    const float* Ar = (const float*)At + ma * 64;
                    int c0 = ((ds << 3) + (q << 1)) ^ (ma & 15);
                    int c1 = c0 ^ 1;              // logical chunk +1 (even base)
                    float4 v0 = *(const float4*)(Ar + c0 * 4);
                    float4 v1 = *(const float4*)(Ar + c1 * 4);
                    unsigned r0, r1, r2, r3;
                    asm("v_cvt_pk_bf16_f32 %0, %1, %2" : "=v"(r0) : "v"(v0.x), "v"(v0.y));
                    asm("v_cvt_pk_bf16_f32 %0, %1, %2" : "=v"(r1) : "v"(v0.z), "v"(v0.w));
                    asm("v_cvt_pk_bf16_f32 %0, %1, %2" : "=v"(r2) : "v"(v1.x), "v"(v1.y));
                    asm("v_cvt_pk_bf16_f32 %0, %1, %2" : "=v"(r3) : "v"(v1.z), "v"(v1.w));
                    int4 tmp;
                    tmp.x = (int)r0; tmp.y = (int)r1; tmp.z = (int)r2; tmp.w = (int)r3;
                    __builtin_memcpy(&a[i], &tmp, 16);
                } else {
                    a[i] = *(bf16x8*)(&At[ma * 64 + ((((ds << 2) + q) ^ (ma & 7)) << 3)]);
                }
            }
#pragma unroll
            for (int j = 0; j < 4; ++j) {
                int nb = wn * 64 + j * 16 + l16;
                b[j] = *(bf16x8*)(&Bt[nb * 64 + ((((ds << 2) + q) ^ (nb & 7)) << 3)]);
            }
#pragma unroll
            for (int i = 0; i < MI; ++i)
#pragma unroll
                for (int j = 0; j < 4; ++j)
                    acc[i][j] = __builtin_amdgcn_mfma_f32_16x16x32_bf16(a[i], b[j], acc[i][j], 0, 0, 0);
        }
    }

    bool isK = (OM != 3) || (nBase < 512);
#pragma unroll
    for (int j = 0; j < 4; ++j) {
        int col = nBase + wn * 64 + j * 16 + l16;
        float bv;
        if constexpr (OM == 3) bv = isK ? bias[col] : bias2res[col - 512];
        else bv = bias[col];
#pragma unroll
        for (int i = 0; i < MI; ++i) {
#pragma unroll
            for (int r = 0; r < 4; ++r) {
                int row = mBase + (BN == 128 ? wm * 32 : wm * 16) + i * 16 + q * 4 + r;
                float v = acc[i][j][r] + bv;
                if constexpr (OM == 1) {
                    v += bias2res[(size_t)row * 512 + col];
                    ((float*)Cv)[(size_t)row * 512 + col] = v;
                } else if constexpr (OM == 0) {
                    ((u16*)Cv)[(size_t)row * 512 + col] = f2b(v * oscale);
                } else {
                    if (isK) {
                        ((u16*)Cv)[(size_t)row * 512 + col] = f2b(v);
                    } else {
                        int colv = col - 512;
                        int g = row >> 7, m2 = ((row & 127) << 3) + (colv >> 6), d = colv & 63;
                        ((u16*)Cv2)[(size_t)((g << 6) + d) * 1024 + m2] = f2b(v);
                    }
                }
            }
        }
    }
}

// ---------------------------------------------------------------------------
// Launch 2: Q-GEMM (blocks 0..1023, f32 A from x directly) U KV-GEMM
// (1024..2047, bf16 A from xp). LDS = At 16 KB + Bt 16 KB = 32 KB -> 4/CU.
// ---------------------------------------------------------------------------
__global__ __launch_bounds__(256, 4) void qkv_kernel(const float* __restrict__ x,
                                                     const u16* __restrict__ xp,
                                                     const u16* __restrict__ wT,
                                                     const float* __restrict__ b_q,
                                                     const float* __restrict__ b_k,
                                                     const float* __restrict__ b_v,
                                                     u16* __restrict__ Qw,
                                                     u16* __restrict__ Kw,
                                                     u16* __restrict__ VwT) {
    __shared__ __align__(16) u16 At[64 * 128];    // 16 KB (f32 tile for Q)
    __shared__ __align__(16) u16 Bt[128 * 64];    // 16 KB
    int gid = blockIdx.x;
    if (gid < 1024) {
        gemm_body<0, 128, 256, true>(gid, x, wT, b_q, nullptr, Qw, nullptr, QSCALE, At, Bt);
    } else {
        gemm_body<3, 64, 64, false>(gid - 1024, xp, wT + 262144, b_k, b_v, Kw, VwT, 1.0f, At, Bt);
    }
}

// Launch 4: output projection + f32 residual (bf16 A path, unchanged).
__global__ __launch_bounds__(256, 4) void gemm_o_kernel(const u16* __restrict__ Ow,
                                                        const u16* __restrict__ wTo,
                                                        const float* __restrict__ b_o,
                                                        const float* __restrict__ xres,
                                                        float* __restrict__ out) {
    __shared__ __align__(16) u16 At[64 * 64];
    __shared__ __align__(16) u16 Bt[128 * 64];
    gemm_body<1, 128, 256, false>(blockIdx.x, Ow, wTo, b_o, xres, out, nullptr, 1.0f, At, Bt);
}

// ---------------------------------------------------------------------------
// Launch 3: flash attention (round-9 verified dbuf body; VGPR 52, no spill,
// 52.6 us). QBLK=128, KVBLK=64 double-buffered; single dispatch (round-10
// split regressed). XCD pinning: g = blockIdx.x -> XCD = g&7.
// ---------------------------------------------------------------------------
__global__ __launch_bounds__(256, 4) void attn_kernel(const u16* __restrict__ Q,
                                                      const u16* __restrict__ K,
                                                      const u16* __restrict__ VT_g,
                                                      u16* __restrict__ O) {
    int g = blockIdx.x;       // XCD = g & 7 (round-robin by linear id)
    int qtile = blockIdx.y;   // 0..31
    const u16* Qg = Q + (size_t)g * 262144;
    const u16* Kg = K + (size_t)g * 65536;
    const u16* Vt = VT_g + (size_t)g * 65536;   // [d][m], pitch 1024
    u16* Og = O + (size_t)g * 262144;

    __shared__ __align__(16) u16 Kt[2][64 * 64];   // XOR-8 swizzled [m][d]
    __shared__ __align__(16) u16 VTs[2][64 * 64];  // XOR-8 swizzled [d][m]
    __shared__ __align__(16) u16 Pt[64 * 64];      // XOR-4dw swizzled [n][m]

    int tid = threadIdx.x, lane = tid & 63, wave = tid >> 6;
    int q = lane >> 4, l16 = lane & 15;
    int n0 = qtile * 128;
    int pkey = (l16 & 7) << 2;            // dword-XOR key for Pt
    int prow = (wave * 16 + l16) * 32;    // Pt row base (dwords)
    int* Pt32 = (int*)Pt;

    bf16x8 qf[2][2];
#pragma unroll
    for (int s = 0; s < 2; ++s)
#pragma unroll
        for (int ds = 0; ds < 2; ++ds)
            qf[s][ds] = *(const bf16x8*)(
                &Qg[(size_t)(n0 + s * 64 + wave * 16 + l16) * 64 + ds * 32 + q * 8]);

    f32x4 oacc[2][4] = {};
    float rsum[2] = {0.f, 0.f};

    auto stage = [&](int buf, int kb) {
#pragma unroll
        for (int t = 0; t < 2; ++t) {
            int c = tid + t * 256;                // slot 0..511
            int m = c >> 3, kc = (c & 7) ^ (m & 7);
            gl2lds16(&Kg[(size_t)(kb * 64 + m) * 64 + kc * 8], &Kt[buf][c * 8]);
            gl2lds16(&Vt[(size_t)m * 1024 + kb * 64 + kc * 8], &VTs[buf][c * 8]);
        }
    };

    stage(0, 0);
    asm volatile("s_waitcnt vmcnt(0)" ::: "memory");
    __syncthreads();

    int cur = 0;
#pragma unroll 1
    for (int kb = 0; kb < 16; ++kb) {
        if (kb < 15) stage(cur ^ 1, kb + 1);      // next tile's loads in flight
        const u16* KtB = Kt[cur];
        const u16* VTsB = VTs[cur];
#pragma unroll
        for (int s = 0; s < 2; ++s) {
            // S^T block; p = exp2(z); packed b64 write to Pt[n][m]
#pragma unroll
            for (int cb = 0; cb < 4; ++cb) {
                int m = cb * 16 + l16;
                bf16x8 kf0 = *(const bf16x8*)(&KtB[m * 64 + ((q ^ (m & 7)) << 3)]);
                bf16x8 kf1 = *(const bf16x8*)(&KtB[m * 64 + (((4 + q) ^ (m & 7)) << 3)]);
                f32x4 z = {};
                __builtin_amdgcn_s_setprio(1);
                z = __builtin_amdgcn_mfma_f32_16x16x32_bf16(kf0, qf[s][0], z, 0, 0, 0);
                z = __builtin_amdgcn_mfma_f32_16x16x32_bf16(kf1, qf[s][1], z, 0, 0, 0);
                __builtin_amdgcn_s_setprio(0);
                float p0 = __builtin_amdgcn_exp2f(z[0]);
                float p1 = __builtin_amdgcn_exp2f(z[1]);
                float p2 = __builtin_amdgcn_exp2f(z[2]);
                float p3 = __builtin_amdgcn_exp2f(z[3]);
                rsum[s] += (p0 + p1) + (p2 + p3);
                unsigned w0, w1;
                asm("v_cvt_pk_bf16_f32 %0, %1, %2" : "=v"(w0) : "v"(p0), "v"(p1));
                asm("v_cvt_pk_bf16_f32 %0, %1, %2" : "=v"(w1) : "v"(p2), "v"(p3));
                int2 w;
                w.x = (int)w0;
                w.y = (int)w1;
                int pd = (cb * 8 + q * 2) ^ pkey;
                *(int2*)(&Pt32[prow + pd]) = w;
            }
            // O += P V (same wave wrote Pt rows; DS in-order, no barrier)
#pragma unroll
            for (int ds = 0; ds < 2; ++ds) {
                int pd = (ds * 16 + q * 4) ^ pkey;
                bf16x8 ap = *(bf16x8*)(&Pt32[prow + pd]);
                __builtin_amdgcn_s_setprio(1);
#pragma unroll
                for (int db = 0; db < 4; ++db) {
                    int dd = db * 16 + l16;
                    int jj = ds * 4 + q;
                    bf16x8 vb = *(const bf16x8*)(&VTsB[dd * 64 + ((jj ^ (dd & 7)) << 3)]);
                    oacc[s][db] = __builtin_amdgcn_mfma_f32_16x16x32_bf16(ap, vb, oacc[s][db], 0, 0, 0);
                }
                __builtin_amdgcn_s_setprio(0);
            }
        }
        asm volatile("s_waitcnt vmcnt(0)" ::: "memory");
        __syncthreads();
        cur ^= 1;
    }

    // epilogue: rsum at row n=l16 (partial over quads) -> reduce over quads,
    // then fetch row (q*4+r)'s total via shfl, normalize, store.
#pragma unroll
    for (int s = 0; s < 2; ++s) {
        float v = rsum[s];
        v += __shfl_xor(v, 16, 64);
        v += __shfl_xor(v, 32, 64);
        rsum[s] = v;
    }
    float inv[2][4];
#pragma unroll
    for (int s = 0; s < 2; ++s)
#pragma unroll
        for (int r = 0; r < 4; ++r)
            inv[s][r] = 1.f / __shfl(rsum[s], q * 4 + r, 64);
#pragma unroll
    for (int s = 0; s < 2; ++s)
#pragma unroll
        for (int db = 0; db < 4; ++db)
#pragma unroll
            for (int r = 0; r < 4; ++r) {
                int row = n0 + s * 64 + wave * 16 + q * 4 + r;
                Og[(size_t)row * 64 + db * 16 + l16] = f2b(oacc[s][db][r] * inv[s][r]);
            }
}

// ---------------------------------------------------------------------------
extern "C" void kernel_launch(void* const* d_in, const int* in_sizes, int n_in,
                              void* d_out, int out_size, void* d_ws, size_t ws_size,
                              hipStream_t stream) {
    const float* x   = (const float*)d_in[0];
    const float* w_q = (const float*)d_in[1];
    const float* b_q = (const float*)d_in[2];
    const float* w_k = (const float*)d_in[3];
    const float* b_k = (const float*)d_in[4];
    const float* w_v = (const float*)d_in[5];
    const float* b_v = (const float*)d_in[6];
    const float* w_o = (const float*)d_in[7];
    const float* b_o = (const float*)d_in[8];
    float* out = (float*)d_out;

    char* ws = (char*)d_ws;
    u16* Ow  = (u16*)(ws);                        // 16 MB (16384,512) bf16
    u16* xp  = (u16*)(ws + (16ull << 20));        //  4 MB (4096,512)
    u16* Qw  = (u16*)(ws + (20ull << 20));        // 16 MB (16384,512)
    u16* Kw  = (u16*)(ws + (36ull << 20));        //  4 MB (4096,512)
    u16* VwT = (u16*)(ws + (40ull << 20));        //  4 MB 32x(64,1024)
    u16* wT  = (u16*)(ws + (44ull << 20));        //  2 MB: 4 x 512x512 bf16

    // L1: wtrans U pool (both read raw inputs; cvt stage eliminated)
    prep_kernel<<<1280, 256, 0, stream>>>(x, w_q, w_k, w_v, w_o, wT, xp);
    // L2: Q projection (f32 A direct from x) U fused K|V projection
    qkv_kernel<<<2048, 256, 0, stream>>>(x, xp, wT, b_q, b_k, b_v, Qw, Kw, VwT);
    // L3: attention: 32 groups (x: XCD-pinned) x 32 q-tiles (y)
    attn_kernel<<<dim3(32, 32), 256, 0, stream>>>(Qw, Kw, VwT, Ow);
    // L4: output projection + f32 residual
    gemm_o_kernel<<<1024, 256, 0, stream>>>(Ow, wT + 786432, b_o, x, out);
}

// Round 12
// 188.364 us; speedup vs baseline: 1.1408x; 1.0325x over previous
//
#include <hip/hip_runtime.h>
#include <hip/hip_bf16.h>
#include <math.h>

typedef short bf16x8 __attribute__((ext_vector_type(8)));
typedef float f32x4 __attribute__((ext_vector_type(4)));
typedef float f32x16 __attribute__((ext_vector_type(16)));
typedef unsigned short u16;

__device__ inline float b2f(u16 h) {
    unsigned int u = ((unsigned int)h) << 16;
    float f;
    __builtin_memcpy(&f, &u, 4);
    return f;
}

__device__ inline u16 f2b(float f) {
    unsigned int u;
    __builtin_memcpy(&u, &f, 4);
    unsigned int lsb = (u >> 16) & 1u;
    u += 0x7fffu + lsb;
    return (u16)(u >> 16);
}

// async 16B global -> LDS (wave-uniform base + lane*16 at all call sites)
__device__ __forceinline__ void gl2lds16(const u16* g, u16* l) {
    __builtin_amdgcn_global_load_lds(
        (const __attribute__((address_space(1))) unsigned int*)g,
        (__attribute__((address_space(3))) unsigned int*)l,
        16, 0, 0);
}

#define PITCH 72   // wtrans scratch pitch

// log2(e) / 8  (softmax temperature sqrt(64)=8 folded into Q projection)
#define QSCALE 0.18033688011112042f

// ---------------------------------------------------------------------------
// Launch 1: prep = wtrans (blocks 0..255) U pool (256..1279). cvt eliminated
// (round 11): Q-GEMM stages f32 x directly; pool reads f32 x.
// ---------------------------------------------------------------------------
__global__ __launch_bounds__(256) void prep_kernel(const float* __restrict__ x,
                                                   const float* __restrict__ w0,
                                                   const float* __restrict__ w1,
                                                   const float* __restrict__ w2,
                                                   const float* __restrict__ w3,
                                                   u16* __restrict__ wt,
                                                   u16* __restrict__ xp) {
    __shared__ u16 T[64 * PITCH];
    int tid = threadIdx.x;
    if (blockIdx.x >= 256) {            // ---- pool: TF avg 3x3/s2 SAME, f32 in
        int idx = (blockIdx.x - 256) * 256 + tid;   // 262,144 = (4,32,32,64)
        int c8 = idx & 63;
        int j = (idx >> 6) & 31;
        int i = (idx >> 11) & 31;
        int b = idx >> 16;
        int r0 = 2 * i, c0 = 2 * j;
        int rmax = min(r0 + 3, 64), cmax = min(c0 + 3, 64);
        float acc[8] = {};
        for (int r = r0; r < rmax; ++r)
            for (int cc = c0; cc < cmax; ++cc) {
                const float* p = &x[(size_t)((((b << 6) + r) << 6) + cc) * 512 + c8 * 8];
                float4 v0 = *(const float4*)p;
                float4 v1 = *(const float4*)(p + 4);
                acc[0] += v0.x; acc[1] += v0.y; acc[2] += v0.z; acc[3] += v0.w;
                acc[4] += v1.x; acc[5] += v1.y; acc[6] += v1.z; acc[7] += v1.w;
            }
        float inv = 1.f / (float)((rmax - r0) * (cmax - c0));
        u16 o[8];
#pragma unroll
        for (int t = 0; t < 8; ++t) o[t] = f2b(acc[t] * inv);
        *(int4*)(&xp[(size_t)idx * 8]) = *(int4*)o;
        return;
    }
    // ---- wtrans: transpose+convert four 512x512 f32 weights to WT[n][k]
    int t5 = blockIdx.x;                // 0..255
    int bx = t5 & 7, by = (t5 >> 3) & 7, bz = t5 >> 6;
    const float* W = bz == 0 ? w0 : bz == 1 ? w1 : bz == 2 ? w2 : w3;
    u16* WT = wt + (size_t)bz * 262144;
    int nB = bx * 64, kB = by * 64;
#pragma unroll
    for (int t = 0; t < 4; ++t) {
        int e = tid + t * 256;
        int r = e >> 4, c4 = (e & 15) * 4;
        float4 v = *(const float4*)(&W[(size_t)(kB + r) * 512 + nB + c4]);
        u16* dst = &T[r * PITCH + c4];
        dst[0] = f2b(v.x); dst[1] = f2b(v.y); dst[2] = f2b(v.z); dst[3] = f2b(v.w);
    }
    __syncthreads();
    int n = tid & 63, kg = tid >> 6;
#pragma unroll
    for (int p = 0; p < 2; ++p) {
        int k0 = (kg + p * 4) * 8;
        u16 tmp[8];
#pragma unroll
        for (int i = 0; i < 8; ++i) tmp[i] = T[(k0 + i) * PITCH + n];
        *(int4*)(&WT[(size_t)(nB + n) * 512 + kB + k0]) = *(int4*)tmp;
    }
}

// ---------------------------------------------------------------------------
// GEMM body (round-6/11 verified): tile 64xBN, BK=64, 4 waves, single-buffer
// LDS. AF32: A is f32 (x itself), converted in-reg via v_cvt_pk_bf16_f32.
// XCD remap: bid = nBlk*GY + mBlk, GY%8==0.
// ---------------------------------------------------------------------------
template <int OM, int BN, int GY, bool AF32>
__device__ __forceinline__ void gemm_body(int bid,
                                          const void* __restrict__ Av,
                                          const u16* __restrict__ WT,
                                          const float* __restrict__ bias,
                                          const float* __restrict__ bias2res,
                                          void* __restrict__ Cv,
                                          void* __restrict__ Cv2,
                                          float oscale,
                                          u16* At, u16* Bt) {
    int tid = threadIdx.x, lane = tid & 63, wave = tid >> 6;
    int q = lane >> 4, l16 = lane & 15;
    constexpr int MI = (BN == 128) ? 2 : 1;
    int wm, wn;
    if constexpr (BN == 128) { wm = wave & 1; wn = wave >> 1; }
    else                     { wm = wave;     wn = 0; }
    int nBlk = bid / GY;
    int mBlk = bid - nBlk * GY;
    int nBase = nBlk * BN, mBase = mBlk * 64;
    f32x4 acc[MI][4] = {};

    for (int kk = 0; kk < 512; kk += 64) {
        __syncthreads();
        if constexpr (AF32) {
            const float* Af = (const float*)Av;
#pragma unroll
            for (int t = 0; t < 4; ++t) {         // At f32: 1024 16B slots
                int c = tid + t * 256;
                int m = c >> 4, kc = (c & 15) ^ (m & 15);
                gl2lds16((const u16*)&Af[(size_t)(mBase + m) * 512 + kk + kc * 4],
                         &At[c * 8]);
            }
        } else {
            const u16* Ab = (const u16*)Av;
#pragma unroll
            for (int t = 0; t < 2; ++t) {         // At bf16: 512 slots
                int c = tid + t * 256;
                int m = c >> 3, kc = (c & 7) ^ (m & 7);
                gl2lds16(&Ab[(size_t)(mBase + m) * 512 + kk + kc * 8], &At[c * 8]);
            }
        }
#pragma unroll
        for (int t = 0; t < BN / 32; ++t) {       // Bt: BN*8 chunk slots
            int c = tid + t * 256;
            int m = c >> 3, kc = (c & 7) ^ (m & 7);
            gl2lds16(&WT[(size_t)(nBase + m) * 512 + kk + kc * 8], &Bt[c * 8]);
        }
        __syncthreads();
#pragma unroll
        for (int ds = 0; ds < 2; ++ds) {
            bf16x8 a[MI], b[4];
#pragma unroll
            for (int i = 0; i < MI; ++i) {
                int ma = (BN == 128 ? wm * 32 : wm * 16) + i * 16 + l16;
                if constexpr (AF32) {
                    const float* Ar = (const float*)At + ma * 64;
                    int c0 = ((ds << 3) + (q << 1)) ^ (ma & 15);
                    int c1 = c0 ^ 1;              // logical chunk +1 (even base)
                    float4 v0 = *(const float4*)(Ar + c0 * 4);
                    float4 v1 = *(const float4*)(Ar + c1 * 4);
                    unsigned r0, r1, r2, r3;
                    asm("v_cvt_pk_bf16_f32 %0, %1, %2" : "=v"(r0) : "v"(v0.x), "v"(v0.y));
                    asm("v_cvt_pk_bf16_f32 %0, %1, %2" : "=v"(r1) : "v"(v0.z), "v"(v0.w));
                    asm("v_cvt_pk_bf16_f32 %0, %1, %2" : "=v"(r2) : "v"(v1.x), "v"(v1.y));
                    asm("v_cvt_pk_bf16_f32 %0, %1, %2" : "=v"(r3) : "v"(v1.z), "v"(v1.w));
                    int4 tmp;
                    tmp.x = (int)r0; tmp.y = (int)r1; tmp.z = (int)r2; tmp.w = (int)r3;
                    __builtin_memcpy(&a[i], &tmp, 16);
                } else {
                    a[i] = *(bf16x8*)(&At[ma * 64 + ((((ds << 2) + q) ^ (ma & 7)) << 3)]);
                }
            }
#pragma unroll
            for (int j = 0; j < 4; ++j) {
                int nb = wn * 64 + j * 16 + l16;
                b[j] = *(bf16x8*)(&Bt[nb * 64 + ((((ds << 2) + q) ^ (nb & 7)) << 3)]);
            }
#pragma unroll
            for (int i = 0; i < MI; ++i)
#pragma unroll
                for (int j = 0; j < 4; ++j)
                    acc[i][j] = __builtin_amdgcn_mfma_f32_16x16x32_bf16(a[i], b[j], acc[i][j], 0, 0, 0);
        }
    }

    bool isK = (OM != 3) || (nBase < 512);
#pragma unroll
    for (int j = 0; j < 4; ++j) {
        int col = nBase + wn * 64 + j * 16 + l16;
        float bv;
        if constexpr (OM == 3) bv = isK ? bias[col] : bias2res[col - 512];
        else bv = bias[col];
#pragma unroll
        for (int i = 0; i < MI; ++i) {
#pragma unroll
            for (int r = 0; r < 4; ++r) {
                int row = mBase + (BN == 128 ? wm * 32 : wm * 16) + i * 16 + q * 4 + r;
                float v = acc[i][j][r] + bv;
                if constexpr (OM == 1) {
                    v += bias2res[(size_t)row * 512 + col];
                    ((float*)Cv)[(size_t)row * 512 + col] = v;
                } else if constexpr (OM == 0) {
                    ((u16*)Cv)[(size_t)row * 512 + col] = f2b(v * oscale);
                } else {
                    if (isK) {
                        ((u16*)Cv)[(size_t)row * 512 + col] = f2b(v);
                    } else {
                        int colv = col - 512;
                        int g = row >> 7, m2 = ((row & 127) << 3) + (colv >> 6), d = colv & 63;
                        ((u16*)Cv2)[(size_t)((g << 6) + d) * 1024 + m2] = f2b(v);
                    }
                }
            }
        }
    }
}

// ---------------------------------------------------------------------------
// Launch 2: Q-GEMM (blocks 0..1023, f32 A from x) U KV-GEMM (1024..2047).
// ---------------------------------------------------------------------------
__global__ __launch_bounds__(256, 4) void qkv_kernel(const float* __restrict__ x,
                                                     const u16* __restrict__ xp,
                                                     const u16* __restrict__ wT,
                                                     const float* __restrict__ b_q,
                                                     const float* __restrict__ b_k,
                                                     const float* __restrict__ b_v,
                                                     u16* __restrict__ Qw,
                                                     u16* __restrict__ Kw,
                                                     u16* __restrict__ VwT) {
    __shared__ __align__(16) u16 At[64 * 128];    // 16 KB (f32 tile for Q)
    __shared__ __align__(16) u16 Bt[128 * 64];    // 16 KB
    int gid = blockIdx.x;
    if (gid < 1024) {
        gemm_body<0, 128, 256, true>(gid, x, wT, b_q, nullptr, Qw, nullptr, QSCALE, At, Bt);
    } else {
        gemm_body<3, 64, 64, false>(gid - 1024, xp, wT + 262144, b_k, b_v, Kw, VwT, 1.0f, At, Bt);
    }
}

// Launch 4: output projection + f32 residual.
__global__ __launch_bounds__(256, 4) void gemm_o_kernel(const u16* __restrict__ Ow,
                                                        const u16* __restrict__ wTo,
                                                        const float* __restrict__ b_o,
                                                        const float* __restrict__ xres,
                                                        float* __restrict__ out) {
    __shared__ __align__(16) u16 At[64 * 64];
    __shared__ __align__(16) u16 Bt[128 * 64];
    gemm_body<1, 128, 256, false>(blockIdx.x, Ow, wTo, b_o, xres, out, nullptr, 1.0f, At, Bt);
}

// ---------------------------------------------------------------------------
// Launch 3: flash attention v2 -- 32x32 swapped-QK, in-register softmax.
// DIAGNOSIS (round 12): old kernel was LDS-BW-bound: ~40 KB of DS traffic
// per wave-tile (K-frags 16 KB + V-frags 16 KB + Pt round-trip 8 KB) ->
// ~5120 clk/CU/tile floor, ~34 us of the 55 -- which is why dbuf (R9),
// setprio (R5) and occupancy (R8) were all null.
// FIX: mfma_32x32x16(A=K, B=Q) puts S^T col n = lane&31 -> P is LANE-LOCAL.
// exp2 -> cvt_pk -> 4x v_permlane32_swap_b32 reshape D0..D7 in place into
// the PV A-fragments (k=(lane>>5)*8+e slices; layout hand-verified). P never
// touches LDS: per wave-tile DS = 8 K-frag + 8 V-frag b128 = 16 KB (2.4x
// less); Pt buffer deleted (LDS 40->32 KB); rsum lane-local (1 shfl_xor at
// end). Each wave owns 32 q-rows (QBLK=128, 4 waves). KVBLK=64 dbuf staging,
// XCD pinning (g->XCD g&7) kept from R9/R11 verified code.
// ---------------------------------------------------------------------------
__global__ __launch_bounds__(256, 4) void attn_kernel(const u16* __restrict__ Q,
                                                      const u16* __restrict__ K,
                                                      const u16* __restrict__ VT_g,
                                                      u16* __restrict__ O) {
    int g = blockIdx.x;       // XCD = g & 7 (round-robin by linear id)
    int qtile = blockIdx.y;   // 0..31
    const u16* Qg = Q + (size_t)g * 262144;
    const u16* Kg = K + (size_t)g * 65536;
    const u16* Vt = VT_g + (size_t)g * 65536;   // [d][m], pitch 1024
    u16* Og = O + (size_t)g * 262144;

    __shared__ __align__(16) u16 Kt[2][64 * 64];   // XOR-8 swizzled [m][d]
    __shared__ __align__(16) u16 VTs[2][64 * 64];  // XOR-8 swizzled [d][m]

    int tid = threadIdx.x, lane = tid & 63, wave = tid >> 6;
    int l32 = lane & 31, h = lane >> 5;
    int w0 = qtile * 128 + wave * 32;   // this wave's 32 q-rows

    // Q fragments (B-operand, col n = l32, k(d) = h*8+e): qf[j] covers d-slice j*16
    bf16x8 qf[4];
#pragma unroll
    for (int j = 0; j < 4; ++j)
        qf[j] = *(const bf16x8*)(&Qg[(size_t)(w0 + l32) * 64 + j * 16 + h * 8]);

    f32x16 oacc[2] = {};
    float rsum = 0.f;

    auto stage = [&](int buf, int kb) {
#pragma unroll
        for (int t = 0; t < 2; ++t) {
            int c = tid + t * 256;                // slot 0..511
            int m = c >> 3, kc = (c & 7) ^ (m & 7);
            gl2lds16(&Kg[(size_t)(kb * 64 + m) * 64 + kc * 8], &Kt[buf][c * 8]);
            gl2lds16(&Vt[(size_t)m * 1024 + kb * 64 + kc * 8], &VTs[buf][c * 8]);
        }
    };

    stage(0, 0);
    asm volatile("s_waitcnt vmcnt(0)" ::: "memory");
    __syncthreads();

    int cur = 0;
#pragma unroll 1
    for (int kb = 0; kb < 16; ++kb) {
        if (kb < 15) stage(cur ^ 1, kb + 1);      // next tile's loads in flight
        const u16* KtB = Kt[cur];
        const u16* VTsB = VTs[cur];
#pragma unroll
        for (int mb = 0; mb < 2; ++mb) {
            // ---- QK: S^T[m 32][n 32] over d=64 (4 mfma). col n = l32 (lane-local).
            int m = mb * 32 + l32;                // A row
            f32x16 z = {};
            __builtin_amdgcn_s_setprio(1);
#pragma unroll
            for (int j = 0; j < 4; ++j) {
                int slot = (j * 2 + h) ^ (m & 7);
                bf16x8 kf = *(const bf16x8*)(&KtB[m * 64 + slot * 8]);
                z = __builtin_amdgcn_mfma_f32_32x32x16_bf16(kf, qf[j], z, 0, 0, 0);
            }
            __builtin_amdgcn_s_setprio(0);
            // ---- softmax numerator, all in-register
            float p[16];
#pragma unroll
            for (int e = 0; e < 16; ++e) {
                p[e] = __builtin_amdgcn_exp2f(z[e]);
                rsum += p[e];
            }
            unsigned D[8];
#pragma unroll
            for (int i = 0; i < 8; ++i)
                asm("v_cvt_pk_bf16_f32 %0, %1, %2" : "=v"(D[i]) : "v"(p[2 * i]), "v"(p[2 * i + 1]));
            // reshape to PV A-fragments: dst.lo <-> src.hi swaps
            asm("v_permlane32_swap_b32 %0, %1" : "+v"(D[2]), "+v"(D[0]));
            asm("v_permlane32_swap_b32 %0, %1" : "+v"(D[3]), "+v"(D[1]));
            asm("v_permlane32_swap_b32 %0, %1" : "+v"(D[6]), "+v"(D[4]));
            asm("v_permlane32_swap_b32 %0, %1" : "+v"(D[7]), "+v"(D[5]));
            bf16x8 fr[2];
            __builtin_memcpy(&fr[0], &D[0], 16);
            __builtin_memcpy(&fr[1], &D[4], 16);
            // ---- PV: O[n 32][d 64] += P[n][m-slice 16] V[m][d] (4 mfma)
            __builtin_amdgcn_s_setprio(1);
#pragma unroll
            for (int ms = 0; ms < 2; ++ms)
#pragma unroll
                for (int db = 0; db < 2; ++db) {
                    int d = db * 32 + l32;
                    int c = mb * 4 + ms * 2 + h;
                    bf16x8 vb = *(const bf16x8*)(&VTsB[d * 64 + ((c ^ (d & 7)) << 3)]);
                    oacc[db] = __builtin_amdgcn_mfma_f32_32x32x16_bf16(fr[ms], vb, oacc[db], 0, 0, 0);
                }
            __builtin_amdgcn_s_setprio(0);
        }
        asm volatile("s_waitcnt vmcnt(0)" ::: "memory");
        __syncthreads();
        cur ^= 1;
    }

    // epilogue: rsum halves live at lanes n and n+32 -> combine; normalize.
    float rs = rsum + __shfl_xor(rsum, 32, 64);
    float inv[16];
#pragma unroll
    for (int r = 0; r < 16; ++r) {
        int row = (r & 3) + 8 * (r >> 2) + 4 * h;
        inv[r] = 1.f / __shfl(rs, row, 64);
    }
#pragma unroll
    for (int db = 0; db < 2; ++db)
#pragma unroll
        for (int r = 0; r < 16; ++r) {
            int row = (r & 3) + 8 * (r >> 2) + 4 * h;
            Og[(size_t)(w0 + row) * 64 + db * 32 + l32] = f2b(oacc[db][r] * inv[r]);
        }
}

// ---------------------------------------------------------------------------
extern "C" void kernel_launch(void* const* d_in, const int* in_sizes, int n_in,
                              void* d_out, int out_size, void* d_ws, size_t ws_size,
                              hipStream_t stream) {
    const float* x   = (const float*)d_in[0];
    const float* w_q = (const float*)d_in[1];
    const float* b_q = (const float*)d_in[2];
    const float* w_k = (const float*)d_in[3];
    const float* b_k = (const float*)d_in[4];
    const float* w_v = (const float*)d_in[5];
    const float* b_v = (const float*)d_in[6];
    const float* w_o = (const float*)d_in[7];
    const float* b_o = (const float*)d_in[8];
    float* out = (float*)d_out;

    char* ws = (char*)d_ws;
    u16* Ow  = (u16*)(ws);                        // 16 MB (16384,512) bf16
    u16* xp  = (u16*)(ws + (16ull << 20));        //  4 MB (4096,512)
    u16* Qw  = (u16*)(ws + (20ull << 20));        // 16 MB (16384,512)
    u16* Kw  = (u16*)(ws + (36ull << 20));        //  4 MB (4096,512)
    u16* VwT = (u16*)(ws + (40ull << 20));        //  4 MB 32x(64,1024)
    u16* wT  = (u16*)(ws + (44ull << 20));        //  2 MB: 4 x 512x512 bf16

    // L1: wtrans U pool (both read raw inputs; cvt stage eliminated)
    prep_kernel<<<1280, 256, 0, stream>>>(x, w_q, w_k, w_v, w_o, wT, xp);
    // L2: Q projection (f32 A direct from x) U fused K|V projection
    qkv_kernel<<<2048, 256, 0, stream>>>(x, xp, wT, b_q, b_k, b_v, Qw, Kw, VwT);
    // L3: attention: 32 groups (x: XCD-pinned) x 32 q-tiles (y)
    attn_kernel<<<dim3(32, 32), 256, 0, stream>>>(Qw, Kw, VwT, Ow);
    // L4: output projection + f32 residual
    gemm_o_kernel<<<1024, 256, 0, stream>>>(Ow, wT + 786432, b_o, x, out);
}